// Round 2
// baseline (180.450 us; speedup 1.0000x reference)
//
#include <hip/hip_runtime.h>
#include <hip/hip_bf16.h>

typedef __bf16 bf16;
typedef __bf16 bf16x4 __attribute__((ext_vector_type(4)));
typedef __bf16 bf16x8 __attribute__((ext_vector_type(8)));
typedef float  f32x4  __attribute__((ext_vector_type(4)));

#define NEG_INF (-1e9f)
#define N_SCENES 2048

// ---------------------------------------------------------------------------
// Prep: block 0 computes exclusive prefix sum of agents_per_sample (B=2048);
// blocks 1..64 convert w_in / w_out fp32 -> bf16 into workspace.
// ---------------------------------------------------------------------------
__global__ __launch_bounds__(256) void prep_kernel(
    const float* __restrict__ w_in, const float* __restrict__ w_out,
    const int* __restrict__ agents,
    bf16* __restrict__ w_in_b, bf16* __restrict__ w_out_b, int* __restrict__ offs)
{
    __shared__ int tot[256];
    const int t = threadIdx.x;
    if (blockIdx.x == 0) {
        int loc[8]; int s = 0;
        #pragma unroll
        for (int j = 0; j < 8; ++j) { loc[j] = agents[t * 8 + j]; s += loc[j]; }
        tot[t] = s;
        __syncthreads();
        for (int o = 1; o < 256; o <<= 1) {
            int v = (t >= o) ? tot[t - o] : 0;
            __syncthreads();
            tot[t] += v;
            __syncthreads();
        }
        int run = tot[t] - s;
        #pragma unroll
        for (int j = 0; j < 8; ++j) { offs[t * 8 + j] = run; run += loc[j]; }
    } else {
        int i = (blockIdx.x - 1) * 1024 + t * 4;
        float4 v; bf16* dst;
        if (i < 49152) { v = *(const float4*)(w_in + i);            dst = w_in_b + i; }
        else           { v = *(const float4*)(w_out + (i - 49152)); dst = w_out_b + (i - 49152); }
        bf16x4 o = { (bf16)v.x, (bf16)v.y, (bf16)v.z, (bf16)v.w };
        *(bf16x4*)dst = o;
    }
}

// ---------------------------------------------------------------------------
// Fused attention: one block (4 waves) per scene; wave w owns head w end-to-end.
// Wave-private LDS region (6144 bf16 = 12 KB): qk [64][64] (q cols 0..31,
// k cols 32..63; P overlays k, ctx overlays q) + vT [32][64]. Total 48 KB
// -> 3 blocks/CU. One __syncthreads (before out-proj, which reads all heads'
// ctx). All LDS tiles XOR-swizzle their 16-B chunks: c' = c ^ (row & 7),
// keeping 16-B alignment for ds_read_b128 with <=2-way conflicts.
// MFMA 16x16x32_bf16 layouts (HW-verified):
//   A[m=lane&15][k=(lane>>4)*8+j], B[k=(lane>>4)*8+j][n=lane&15] (BT row-major),
//   C/D: col=lane&15, row=(lane>>4)*4+reg.
// m-tiles beyond ceil(nb/16) are skipped (wave-uniform nb); boundary tiles are
// zero-padded (x frags, P, vT) so no uninitialized LDS reaches an MFMA.
// ---------------------------------------------------------------------------
__global__ __launch_bounds__(256, 3) void attn_kernel(
    const float* __restrict__ att_in,
    const float* __restrict__ b_in, const float* __restrict__ b_out,
    const bf16* __restrict__ w_in_b, const bf16* __restrict__ w_out_b,
    const int* __restrict__ agents, const int* __restrict__ offs,
    float* __restrict__ out)
{
    __shared__ bf16 s_lds[4 * 6144];   // 48 KB

    const int b    = blockIdx.x;
    const int tid  = threadIdx.x;
    const int lane = tid & 63;
    const int w    = tid >> 6;         // wave id == head id
    const int h    = w;
    const int r    = lane & 15;
    const int qd   = lane >> 4;        // quad 0..3
    const int r7   = lane & 7;
    const int nb   = agents[b];
    const int off  = offs[b];
    const int mtc  = (nb + 15) >> 4;   // live m-tiles (1..4)
    const int mt16 = mtc << 4;

    bf16* qk = s_lds + w * 6144;       // [64][64], swizzled
    bf16* vT = qk + 4096;              // [32][64], swizzled: vT[hd][agent]

    // ---- early: zero-store output rows [mt16, 64) (independent work) ----
    {
        const float4 z4 = make_float4(0.f, 0.f, 0.f, 0.f);
        const int nz = (64 - mt16) * 32;
        for (int i = tid; i < nz; i += 256) {
            int row = mt16 + (i >> 5);
            *(float4*)(out + ((size_t)b * 64 + row) * 128 + (i & 31) * 4) = z4;
        }
    }

    // ---- zero vT boundary key-tile [mt16, mt16+16) when mtc odd (PV K=32 pads) ----
    if (mtc & 1) {
        int row = lane >> 1, half = lane & 1;
        int c = (2 * mtc + half) ^ (row & 7);
        bf16x8 z8 = {(bf16)0.f,(bf16)0.f,(bf16)0.f,(bf16)0.f,
                     (bf16)0.f,(bf16)0.f,(bf16)0.f,(bf16)0.f};
        *(bf16x8*)(vT + row * 64 + c * 8) = z8;
    }

    // ---- x A-fragments straight from global (rows >= nb -> 0) ----
    bf16x8 xa[4][4];
    #pragma unroll
    for (int mt = 0; mt < 4; ++mt)
        #pragma unroll
        for (int ks = 0; ks < 4; ++ks) {
            float4 lo = make_float4(0.f,0.f,0.f,0.f), hi = lo;
            int row = mt * 16 + r;
            if (row < nb) {
                const float* p = att_in + (((size_t)(off + row)) << 7) + ks * 32 + qd * 8;
                lo = *(const float4*)p;
                hi = *(const float4*)(p + 4);
            }
            xa[mt][ks] = (bf16x8){(bf16)lo.x,(bf16)lo.y,(bf16)lo.z,(bf16)lo.w,
                                  (bf16)hi.x,(bf16)hi.y,(bf16)hi.z,(bf16)hi.w};
        }

    // ---- stage 1: this head's q,k,v tiles (6 n-tiles), wave-private ----
    #pragma unroll
    for (int t = 0; t < 6; ++t) {
        const int kind = t >> 1, sub = t & 1;       // 0=q,1=k,2=v
        const int j0 = kind * 128 + h * 32 + sub * 16;
        bf16x8 wb[4];
        #pragma unroll
        for (int ks = 0; ks < 4; ++ks)
            wb[ks] = *(const bf16x8*)(w_in_b + (size_t)(j0 + r) * 128 + ks * 32 + qd * 8);
        const float bias = b_in[j0 + r];
        #pragma unroll
        for (int mt = 0; mt < 4; ++mt) {
            if (mt < mtc) {
                f32x4 acc = {0.f, 0.f, 0.f, 0.f};
                #pragma unroll
                for (int ks = 0; ks < 4; ++ks)
                    acc = __builtin_amdgcn_mfma_f32_16x16x32_bf16(xa[mt][ks], wb[ks], acc, 0, 0, 0);
                if (kind < 2) {
                    // q cols 0..31, k cols 32..63; scalar C-layout write
                    int chunk = kind * 4 + sub * 2 + (r >> 3);
                    #pragma unroll
                    for (int i = 0; i < 4; ++i) {
                        int row = mt * 16 + qd * 4 + i;
                        int c = chunk ^ (row & 7);
                        qk[row * 64 + c * 8 + r7] = (bf16)(acc[i] + bias);
                    }
                } else {
                    // vT[hd][agent]: 4 consecutive agents -> one 8-B write
                    int row = sub * 16 + r;                    // hd within head
                    int c = (2 * mt + (qd >> 1)) ^ r7;
                    bf16x4 pk = {(bf16)(acc[0]+bias), (bf16)(acc[1]+bias),
                                 (bf16)(acc[2]+bias), (bf16)(acc[3]+bias)};
                    *(bf16x4*)(vT + row * 64 + c * 8 + (qd & 1) * 4) = pk;
                }
            }
        }
    }

    // ---- stage 2: scores + masked softmax + PV (wave-private) ----
    bf16x8 qa[4], kb[4];
    #pragma unroll
    for (int mt = 0; mt < 4; ++mt)
        if (mt < mtc) {
            int row = mt * 16 + r;
            qa[mt] = *(const bf16x8*)(qk + row * 64 + ((qd) ^ r7) * 8);
            kb[mt] = *(const bf16x8*)(qk + row * 64 + ((4 + qd) ^ r7) * 8);
        }
    f32x4 S[4][4];
    #pragma unroll
    for (int mt = 0; mt < 4; ++mt)
        if (mt < mtc)
            #pragma unroll
            for (int nt = 0; nt < 4; ++nt)
                if (nt < mtc) {
                    f32x4 z = {0.f, 0.f, 0.f, 0.f};
                    S[mt][nt] = __builtin_amdgcn_mfma_f32_16x16x32_bf16(qa[mt], kb[nt], z, 0, 0, 0);
                }

    const float scale = 0.17677669529663687f;       // 1/sqrt(32)
    bool kvalid[4];
    #pragma unroll
    for (int nt = 0; nt < 4; ++nt) kvalid[nt] = (nt < mtc) && ((nt * 16 + r) < nb);
    #pragma unroll
    for (int mt = 0; mt < 4; ++mt)
        if (mt < mtc)
            #pragma unroll
            for (int i = 0; i < 4; ++i) {
                float v[4]; float mx = NEG_INF;
                #pragma unroll
                for (int nt = 0; nt < 4; ++nt) {
                    float val = kvalid[nt] ? S[mt][nt][i] * scale : NEG_INF;
                    v[nt] = val; mx = fmaxf(mx, val);
                }
                mx = fmaxf(mx, __shfl_xor(mx, 1));
                mx = fmaxf(mx, __shfl_xor(mx, 2));
                mx = fmaxf(mx, __shfl_xor(mx, 4));
                mx = fmaxf(mx, __shfl_xor(mx, 8));
                float l = 0.f;
                #pragma unroll
                for (int nt = 0; nt < 4; ++nt) { v[nt] = __expf(v[nt] - mx); l += v[nt]; }
                l += __shfl_xor(l, 1); l += __shfl_xor(l, 2);
                l += __shfl_xor(l, 4); l += __shfl_xor(l, 8);
                float rl = 1.0f / l;
                #pragma unroll
                for (int nt = 0; nt < 4; ++nt) S[mt][nt][i] = v[nt] * rl;
                // note: S[mt][nt>=mtc] becomes exact 0 here (masked) — safe for P
            }

    // PV: P overlays k (cols 32..63), K=32 chunks; vb from vT
    f32x4 cacc[4][2];
    #pragma unroll
    for (int mt = 0; mt < 4; ++mt)
        #pragma unroll
        for (int n2 = 0; n2 < 2; ++n2)
            cacc[mt][n2] = (f32x4){0.f, 0.f, 0.f, 0.f};
    const int hkc = (mtc + 1) >> 1;
    #pragma unroll
    for (int hk = 0; hk < 2; ++hk)
        if (hk < hkc) {
            #pragma unroll
            for (int mt = 0; mt < 4; ++mt)
                if (mt < mtc)
                    #pragma unroll
                    for (int n2 = 0; n2 < 2; ++n2) {
                        int chunk = 4 + n2 * 2 + (r >> 3);
                        #pragma unroll
                        for (int i = 0; i < 4; ++i) {
                            int row = mt * 16 + qd * 4 + i;
                            int c = chunk ^ (row & 7);
                            qk[row * 64 + c * 8 + r7] = (bf16)S[mt][hk * 2 + n2][i];
                        }
                    }
            bf16x8 vb[2];
            #pragma unroll
            for (int n2 = 0; n2 < 2; ++n2) {
                int row = n2 * 16 + r;
                int c = (hk * 4 + qd) ^ r7;
                vb[n2] = *(const bf16x8*)(vT + row * 64 + c * 8);
            }
            #pragma unroll
            for (int mt = 0; mt < 4; ++mt)
                if (mt < mtc) {
                    int row = mt * 16 + r;
                    bf16x8 pa = *(const bf16x8*)(qk + row * 64 + ((4 + qd) ^ r7) * 8);
                    cacc[mt][0] = __builtin_amdgcn_mfma_f32_16x16x32_bf16(pa, vb[0], cacc[mt][0], 0, 0, 0);
                    cacc[mt][1] = __builtin_amdgcn_mfma_f32_16x16x32_bf16(pa, vb[1], cacc[mt][1], 0, 0, 0);
                }
        }

    // ctx -> qk cols 0..31 (overlays dead q)
    #pragma unroll
    for (int mt = 0; mt < 4; ++mt)
        if (mt < mtc)
            #pragma unroll
            for (int n2 = 0; n2 < 2; ++n2) {
                int chunk = n2 * 2 + (r >> 3);
                #pragma unroll
                for (int i = 0; i < 4; ++i) {
                    int row = mt * 16 + qd * 4 + i;
                    int c = chunk ^ (row & 7);
                    qk[row * 64 + c * 8 + r7] = (bf16)cacc[mt][n2][i];
                }
            }
    __syncthreads();

    // ---- stage 3: out = (ctx @ w_out^T + b_out) * row_mask ----
    #pragma unroll
    for (int t2 = 0; t2 < 2; ++t2) {
        const int j0 = (w * 2 + t2) * 16;
        bf16x8 wo[4];
        #pragma unroll
        for (int ks = 0; ks < 4; ++ks)
            wo[ks] = *(const bf16x8*)(w_out_b + (size_t)(j0 + r) * 128 + ks * 32 + qd * 8);
        const float bias = b_out[j0 + r];
        #pragma unroll
        for (int mt = 0; mt < 4; ++mt)
            if (mt < mtc) {
                f32x4 acc = {0.f, 0.f, 0.f, 0.f};
                #pragma unroll
                for (int ks = 0; ks < 4; ++ks) {
                    int row = mt * 16 + r;
                    bf16x8 ca = *(const bf16x8*)(s_lds + ks * 6144 + row * 64 + (qd ^ r7) * 8);
                    acc = __builtin_amdgcn_mfma_f32_16x16x32_bf16(ca, wo[ks], acc, 0, 0, 0);
                }
                #pragma unroll
                for (int i = 0; i < 4; ++i) {
                    int row = mt * 16 + qd * 4 + i;
                    float val = (row < nb) ? (acc[i] + bias) : 0.f;
                    out[((size_t)b * 64 + row) * 128 + j0 + r] = val;
                }
            }
    }
}

extern "C" void kernel_launch(void* const* d_in, const int* in_sizes, int n_in,
                              void* d_out, int out_size, void* d_ws, size_t ws_size,
                              hipStream_t stream)
{
    const float* att_in = (const float*)d_in[0];
    const float* w_in   = (const float*)d_in[1];
    const float* b_in   = (const float*)d_in[2];
    const float* w_out  = (const float*)d_in[3];
    const float* b_out  = (const float*)d_in[4];
    const int*   agents = (const int*)d_in[5];

    bf16* w_in_b  = (bf16*)d_ws;                         // 49152 * 2B
    bf16* w_out_b = w_in_b + 49152;                      // 16384 * 2B
    int*  offs    = (int*)((char*)d_ws + 98304 + 32768); // 2048 * 4B

    prep_kernel<<<65, 256, 0, stream>>>(w_in, w_out, agents, w_in_b, w_out_b, offs);
    attn_kernel<<<N_SCENES, 256, 0, stream>>>(att_in, b_in, b_out, w_in_b, w_out_b,
                                              agents, offs, (float*)d_out);
}